// Round 8
// baseline (345.402 us; speedup 1.0000x reference)
//
#include <hip/hip_runtime.h>

// FeatureFinetuningLoss: total = (1/C) * sum_{b,c} max(|m_bc - pos_c + eps| - |m_bc - neg_c + eps| + 1, 0)
// m_bc = mean over 196 spatial elems of (qual[b]==1 ? feat : feat_p)[b,c,:,:]
//
// R8: R6 kernel body (best: 185.6 us) + fused single-kernel finish.
//  - Phase 1/2 identical to R6: 32 ch/block, 64-thr single-wave blocks,
//    nt float4 loads in 13/12 bursts (208 KB/CU in flight), LDS transpose.
//  - Finish: each block atomicAdds its partial into one of 64 device-scope
//    float slots in ws, bumps a done counter; the LAST block fetches the 64
//    slots coherently (atomicAdd +0.0f, safe across non-coherent XCD L2s)
//    and writes out[0]. Removes the second dispatch + full-drain tail.
//  - ws[0..63] slots + ws[64] counter zeroed via a tiny hipMemsetAsync node.

#define B_ 128
#define C_ 1024
#define HW_ 196
#define NF4_ 49                       // float4s per channel (784 B)
#define CPB_ 32                       // channels per block
#define NF4B_ (CPB_ * NF4_)           // 1568 f4-sums per block
#define NBLOCKS_ (B_ * C_ / CPB_)     // 4096 -> 16 blocks/CU

typedef float v4f __attribute__((ext_vector_type(4)));

__global__ __launch_bounds__(64, 4) void loss_fused_kernel(
    const float* __restrict__ feat, const float* __restrict__ feat_p,
    const float* __restrict__ af, const int* __restrict__ qual,
    const int* __restrict__ label, float* __restrict__ ws,
    float* __restrict__ out)
{
    __shared__ float lsum[NF4B_];          // 6.27 KB
    const int blk  = blockIdx.x;
    const int b    = blk >> 5;             // 32 blocks per sample
    const int c0   = (blk & 31) << 5;      // first channel of this block
    const int lane = threadIdx.x;          // 0..63

    const int q   = qual[b];               // block-uniform -> scalar
    const int lab = label[b];
    const float* sel = (q == 1 ? feat : feat_p);
    const v4f* base = (const v4f*)(sel + ((size_t)b * C_ + c0) * HW_);

    // ---- Phase 1: 24 full-wave nt float4 loads + 1 half-wave, two bursts ----
    {   // burst A: loads 0..12 (13 KB in flight)
        v4f t[13];
        #pragma unroll
        for (int i = 0; i < 13; ++i)
            t[i] = __builtin_nontemporal_load(&base[i * 64 + lane]);
        #pragma unroll
        for (int i = 0; i < 13; ++i)
            lsum[i * 64 + lane] = (t[i].x + t[i].y) + (t[i].z + t[i].w);
    }
    {   // burst B: loads 13..23 + half-load 24 (lanes 0..31)
        v4f t[11];
        #pragma unroll
        for (int i = 0; i < 11; ++i)
            t[i] = __builtin_nontemporal_load(&base[(13 + i) * 64 + lane]);
        v4f u = (v4f)(0.f);
        if (lane < 32) u = __builtin_nontemporal_load(&base[24 * 64 + lane]);
        #pragma unroll
        for (int i = 0; i < 11; ++i)
            lsum[(13 + i) * 64 + lane] = (t[i].x + t[i].y) + (t[i].z + t[i].w);
        if (lane < 32)
            lsum[24 * 64 + lane] = (u.x + u.y) + (u.z + u.w);
    }
    __syncthreads();

    // ---- Phase 2: lane pair (ch, ch+32) sums channel ch's 49 partials ----
    const int ch   = lane & 31;
    const int half = lane >> 5;
    const float* my = &lsum[ch * NF4_];
    const int start = half * 24;           // half0: j 0..23, half1: j 24..48
    float a0 = 0.f, a1 = 0.f;
    #pragma unroll
    for (int j = 0; j < 24; j += 2) {
        a0 += my[start + j];
        a1 += my[start + j + 1];
    }
    if (half) a0 += my[48];
    float s = a0 + a1;
    s += __shfl_xor(s, 32, 64);            // full channel sum in both halves
    const float mean = s * (1.0f / 196.0f);

    const int c = c0 + ch;
    const float pos = af[lab * C_ + c];
    const float neg = af[(1 - lab) * C_ + c];
    float h = fmaxf(fabsf(mean - pos + 1e-6f) - fabsf(mean - neg + 1e-6f) + 1.0f, 0.0f);

    // each 32-half holds all 32 channel hinges once; butterfly leaves the
    // block partial replicated in every lane
    #pragma unroll
    for (int off = 16; off > 0; off >>= 1)
        h += __shfl_xor(h, off, 64);

    // ---- Fused finish: 64 atomic slots + done-counter; last block writes out ----
    float* slots = ws;                          // ws[0..63]
    unsigned int* counter = (unsigned int*)(ws + 64);
    __shared__ unsigned int s_old;
    if (lane == 0) {
        atomicAdd(&slots[blk & 63], h);         // device-scope
        __threadfence();                        // slot add visible before counter
        s_old = atomicAdd(counter, 1u);
    }
    __syncthreads();
    if (s_old == NBLOCKS_ - 1) {                // last block finishes
        float v = atomicAdd(&slots[lane], 0.0f);  // coherent fetch
        #pragma unroll
        for (int off = 32; off > 0; off >>= 1)
            v += __shfl_xor(v, off, 64);
        if (lane == 0) out[0] = v * (1.0f / (float)C_);
    }
}

extern "C" void kernel_launch(void* const* d_in, const int* in_sizes, int n_in,
                              void* d_out, int out_size, void* d_ws, size_t ws_size,
                              hipStream_t stream) {
    const float* feat   = (const float*)d_in[0];
    const float* feat_p = (const float*)d_in[1];
    const float* af     = (const float*)d_in[2];   // (2, C)
    const int*   qual   = (const int*)d_in[3];
    const int*   label  = (const int*)d_in[4];
    float* out = (float*)d_out;
    float* ws  = (float*)d_ws;                     // 64 slots + counter

    hipMemsetAsync(ws, 0, 65 * sizeof(float), stream);  // zero slots + counter
    loss_fused_kernel<<<NBLOCKS_, 64, 0, stream>>>(feat, feat_p, af, qual, label, ws, out);
}

// Round 9
// 189.384 us; speedup vs baseline: 1.8238x; 1.8238x over previous
//
#include <hip/hip_runtime.h>

// FeatureFinetuningLoss: total = (1/C) * sum_{b,c} max(|m_bc - pos_c + eps| - |m_bc - neg_c + eps| + 1, 0)
// m_bc = mean over 196 spatial elems of (qual[b]==1 ? feat : feat_p)[b,c,:,:]
//
// R9: REVERT to R6 (best: 185.6 us). R7 (rolling pipeline) -1.6 us worse;
// R8 (atomic-fused finish) catastrophic: per-block __threadfence = L2
// writeback x 4096 -> 290 GB/s, 176 us kernel. R6's recipe:
//  - 32 ch/block, 64-thr single-wave blocks, 4096 blocks (16/CU).
//  - NON-TEMPORAL float4 loads (stream-once data; avoids allocating into
//    the poison-filled L2/L3 -> -12.7 us vs cached loads).
//  - 13/12-load bursts (13 KB in flight/wave, ~208 KB/CU outstanding).
//  - LDS transpose, stride-49 reads (2-way bank aliasing = free).
//  - Separate tiny final-reduce dispatch (cheaper than any fused finish).

#define B_ 128
#define C_ 1024
#define HW_ 196
#define NF4_ 49                       // float4s per channel (784 B)
#define CPB_ 32                       // channels per block
#define NF4B_ (CPB_ * NF4_)           // 1568 f4-sums per block
#define NBLOCKS_ (B_ * C_ / CPB_)     // 4096 -> 16 blocks/CU

typedef float v4f __attribute__((ext_vector_type(4)));

__global__ __launch_bounds__(64, 4) void loss_partial_kernel(
    const float* __restrict__ feat, const float* __restrict__ feat_p,
    const float* __restrict__ af, const int* __restrict__ qual,
    const int* __restrict__ label, float* __restrict__ ws)
{
    __shared__ float lsum[NF4B_];          // 6.27 KB
    const int blk  = blockIdx.x;
    const int b    = blk >> 5;             // 32 blocks per sample
    const int c0   = (blk & 31) << 5;      // first channel of this block
    const int lane = threadIdx.x;          // 0..63

    const int q   = qual[b];               // block-uniform -> scalar
    const int lab = label[b];
    const float* sel = (q == 1 ? feat : feat_p);
    const v4f* base = (const v4f*)(sel + ((size_t)b * C_ + c0) * HW_);

    // ---- Phase 1: 24 full-wave nt float4 loads + 1 half-wave, two bursts ----
    {   // burst A: loads 0..12 (13 KB in flight)
        v4f t[13];
        #pragma unroll
        for (int i = 0; i < 13; ++i)
            t[i] = __builtin_nontemporal_load(&base[i * 64 + lane]);
        #pragma unroll
        for (int i = 0; i < 13; ++i)
            lsum[i * 64 + lane] = (t[i].x + t[i].y) + (t[i].z + t[i].w);
    }
    {   // burst B: loads 13..23 + half-load 24 (lanes 0..31)
        v4f t[11];
        #pragma unroll
        for (int i = 0; i < 11; ++i)
            t[i] = __builtin_nontemporal_load(&base[(13 + i) * 64 + lane]);
        v4f u = (v4f)(0.f);
        if (lane < 32) u = __builtin_nontemporal_load(&base[24 * 64 + lane]);
        #pragma unroll
        for (int i = 0; i < 11; ++i)
            lsum[(13 + i) * 64 + lane] = (t[i].x + t[i].y) + (t[i].z + t[i].w);
        if (lane < 32)
            lsum[24 * 64 + lane] = (u.x + u.y) + (u.z + u.w);
    }
    __syncthreads();

    // ---- Phase 2: lane pair (ch, ch+32) sums channel ch's 49 partials ----
    const int ch   = lane & 31;
    const int half = lane >> 5;
    const float* my = &lsum[ch * NF4_];
    const int start = half * 24;           // half0: j 0..23, half1: j 24..48
    float a0 = 0.f, a1 = 0.f;
    #pragma unroll
    for (int j = 0; j < 24; j += 2) {
        a0 += my[start + j];
        a1 += my[start + j + 1];
    }
    if (half) a0 += my[48];
    float s = a0 + a1;
    s += __shfl_xor(s, 32, 64);            // full channel sum in both halves
    const float mean = s * (1.0f / 196.0f);

    const int c = c0 + ch;
    const float pos = af[lab * C_ + c];
    const float neg = af[(1 - lab) * C_ + c];
    float h = fmaxf(fabsf(mean - pos + 1e-6f) - fabsf(mean - neg + 1e-6f) + 1.0f, 0.0f);

    // reduce 32 channel-hinges (each 32-half holds all 32 channels once)
    #pragma unroll
    for (int off = 16; off > 0; off >>= 1)
        h += __shfl_xor(h, off, 64);
    if (lane == 0) ws[blk] = h;
}

__global__ __launch_bounds__(256) void final_reduce_kernel(
    const float* __restrict__ ws, float* __restrict__ out)
{
    const int tid = threadIdx.x;
    float s = 0.0f;
    #pragma unroll
    for (int i = 0; i < NBLOCKS_ / 256; ++i)   // 16 loads
        s += ws[tid + i * 256];
    #pragma unroll
    for (int off = 32; off > 0; off >>= 1)
        s += __shfl_xor(s, off, 64);
    __shared__ float sred[4];
    if ((tid & 63) == 0) sred[tid >> 6] = s;
    __syncthreads();
    if (tid == 0)
        out[0] = ((sred[0] + sred[1]) + (sred[2] + sred[3])) * (1.0f / (float)C_);
}

extern "C" void kernel_launch(void* const* d_in, const int* in_sizes, int n_in,
                              void* d_out, int out_size, void* d_ws, size_t ws_size,
                              hipStream_t stream) {
    const float* feat   = (const float*)d_in[0];
    const float* feat_p = (const float*)d_in[1];
    const float* af     = (const float*)d_in[2];   // (2, C)
    const int*   qual   = (const int*)d_in[3];
    const int*   label  = (const int*)d_in[4];
    float* out = (float*)d_out;
    float* ws  = (float*)d_ws;                     // NBLOCKS_ floats = 16 KB

    loss_partial_kernel<<<NBLOCKS_, 64, 0, stream>>>(feat, feat_p, af, qual, label, ws);
    final_reduce_kernel<<<1, 256, 0, stream>>>(ws, out);
}